// Round 1
// baseline (146.069 us; speedup 1.0000x reference)
//
#include <hip/hip_runtime.h>

#define S_CONST 8
#define K_CONST 10
#define EPSF 1e-8f

// acc layout (doubles in d_ws):
// [0]=sum_b sum_j p1*log(p1)   (note: positive-sign sum of p*log p, log p<0)
// [1]=sum_b sum_j p2*log(p2)
// [2]=sum_b unique_count
// [3]=sum_{s,b} correct
// [4]=sum_{s,b} log_probs*advantage
__global__ void init_accums(double* acc) {
    int i = threadIdx.x;
    if (i < 5) acc[i] = 0.0;
}

__global__ __launch_bounds__(256) void fml_reduce(
        const float* __restrict__ pCS,
        const int* __restrict__ Y,
        const int* __restrict__ s1g,
        const int* __restrict__ s2g,
        double* __restrict__ acc,
        int B)
{
    float ent1 = 0.f, ent2 = 0.f, uniq = 0.f, corr = 0.f, rloo = 0.f;

    int tid = blockIdx.x * blockDim.x + threadIdx.x;
    int stride = gridDim.x * blockDim.x;

    for (int b = tid; b < B; b += stride) {
        // ---- load the 20-float prob row (16B-aligned: 20*4=80 bytes) ----
        const float4* row = reinterpret_cast<const float4*>(pCS + (size_t)b * 20);
        float4 f0 = row[0], f1 = row[1], f2 = row[2], f3 = row[3], f4v = row[4];
        float p1[K_CONST] = {f0.x, f0.y, f0.z, f0.w, f1.x, f1.y, f1.z, f1.w, f2.x, f2.y};
        float p2[K_CONST] = {f2.z, f2.w, f3.x, f3.y, f3.z, f3.w, f4v.x, f4v.y, f4v.z, f4v.w};

        float lg1[K_CONST], lg2[K_CONST];
        #pragma unroll
        for (int j = 0; j < K_CONST; ++j) {
            lg1[j] = logf(p1[j]);          // p >= ~1e-4 >> EPS, reuse for entropy+logprob
            lg2[j] = logf(p2[j]);
            ent1 += p1[j] * lg1[j];
            ent2 += p2[j] * lg2[j];
        }

        int y = Y[b];

        int a1[S_CONST], a2[S_CONST], pr[S_CONST];
        float c[S_CONST];
        float csum = 0.f;
        #pragma unroll
        for (int s = 0; s < S_CONST; ++s) {
            a1[s] = s1g[(size_t)s * B + b];
            a2[s] = s2g[(size_t)s * B + b];
            pr[s] = a1[s] * K_CONST + a2[s];
            c[s]  = (a1[s] + a2[s] == y) ? 1.f : 0.f;
            csum += c[s];
        }
        corr += csum;

        // unique count: # of first occurrences among the 8 pair codes
        #pragma unroll
        for (int i = 0; i < S_CONST; ++i) {
            bool dup = false;
            #pragma unroll
            for (int j = 0; j < i; ++j) dup = dup || (pr[i] == pr[j]);
            uniq += dup ? 0.f : 1.f;
        }

        // rloo: advantage * (lg1[a1] + lg2[a2]) ; register gather via select chain
        #pragma unroll
        for (int s = 0; s < S_CONST; ++s) {
            float adv = c[s] - (csum - c[s]) / 7.0f;   // (S-1+1e-8) rounds to 7.0f
            float g1 = lg1[0], g2 = lg2[0];
            #pragma unroll
            for (int j = 1; j < K_CONST; ++j) {
                g1 = (a1[s] == j) ? lg1[j] : g1;
                g2 = (a2[s] == j) ? lg2[j] : g2;
            }
            rloo += (g1 + g2) * adv;
        }
    }

    // ---- 64-lane butterfly reduce ----
    #pragma unroll
    for (int off = 32; off >= 1; off >>= 1) {
        ent1 += __shfl_xor(ent1, off);
        ent2 += __shfl_xor(ent2, off);
        uniq += __shfl_xor(uniq, off);
        corr += __shfl_xor(corr, off);
        rloo += __shfl_xor(rloo, off);
    }

    __shared__ float red[4][5];
    int lane = threadIdx.x & 63;
    int wave = threadIdx.x >> 6;
    if (lane == 0) {
        red[wave][0] = ent1; red[wave][1] = ent2; red[wave][2] = uniq;
        red[wave][3] = corr; red[wave][4] = rloo;
    }
    __syncthreads();
    if (threadIdx.x == 0) {
        double e1 = 0, e2 = 0, u = 0, cs = 0, rl = 0;
        #pragma unroll
        for (int w = 0; w < 4; ++w) {
            e1 += red[w][0]; e2 += red[w][1]; u += red[w][2];
            cs += red[w][3]; rl += red[w][4];
        }
        atomicAdd(&acc[0], e1);
        atomicAdd(&acc[1], e2);
        atomicAdd(&acc[2], u);
        atomicAdd(&acc[3], cs);
        atomicAdd(&acc[4], rl);
    }
}

__global__ void fml_finalize(const double* __restrict__ acc,
                             const float* __restrict__ base_loss,
                             float* __restrict__ out, int B)
{
    if (threadIdx.x == 0 && blockIdx.x == 0) {
        double dB = (double)B;
        float ent1 = (float)(-acc[0] / dB);           // mean entropy head 1
        float ent2 = (float)(-acc[1] / dB);
        float entropy_loss = -(ent1 + ent2) * 0.5f;
        float diversity = (float)(acc[2] / dB);
        float ratio = diversity / 8.0f;               // max_diversity = min(8,100)=8
        float diversity_loss = -logf(ratio + EPSF);
        float sample_acc = (float)(acc[3] / (dB * (double)S_CONST));
        float rloo_loss  = (float)(-acc[4] / (dB * (double)S_CONST));
        float total = base_loss[0] + 0.01f * entropy_loss + 0.1f * diversity_loss;
        out[0] = total;
        out[1] = rloo_loss;
        out[2] = diversity_loss;
        out[3] = sample_acc;
    }
}

extern "C" void kernel_launch(void* const* d_in, const int* in_sizes, int n_in,
                              void* d_out, int out_size, void* d_ws, size_t ws_size,
                              hipStream_t stream) {
    const float* pCS       = (const float*)d_in[0];
    const float* base_loss = (const float*)d_in[1];
    const int*   Y         = (const int*)d_in[2];
    const int*   s1        = (const int*)d_in[3];
    const int*   s2        = (const int*)d_in[4];
    float* out = (float*)d_out;
    int B = in_sizes[2];

    double* acc = (double*)d_ws;

    init_accums<<<1, 64, 0, stream>>>(acc);

    int block = 256;
    int grid = 2048;                 // 2 rows/thread at B=1M
    fml_reduce<<<grid, block, 0, stream>>>(pCS, Y, s1, s2, acc, B);

    fml_finalize<<<1, 64, 0, stream>>>(acc, base_loss, out, B);
}

// Round 2
// 44.497 us; speedup vs baseline: 3.2826x; 3.2826x over previous
//
#include <hip/hip_runtime.h>

#define S_CONST 8
#define K_CONST 10
#define EPSF 1e-8f
#define ROWS_PER_TILE 256
#define ROW_PAD 21          // 20 floats + 1 pad; gcd(21,32)=1 -> conflict-free row reads

// ws layout: partials[nblocks][4] doubles: {sum p*logp (both heads), uniq, corr, rloo}
__global__ __launch_bounds__(256) void fml_reduce(
        const float* __restrict__ pCS,
        const int* __restrict__ Y,
        const int* __restrict__ s1g,
        const int* __restrict__ s2g,
        double* __restrict__ partials,
        int B)
{
    __shared__ float sp[ROWS_PER_TILE * ROW_PAD];   // 21504 B
    __shared__ float red[4][4];

    float ent = 0.f, uniq = 0.f, corr = 0.f, rloo = 0.f;

    const int tid = threadIdx.x;
    const int ntiles = (B + ROWS_PER_TILE - 1) / ROWS_PER_TILE;

    for (int tile = blockIdx.x; tile < ntiles; tile += gridDim.x) {
        const int base = tile * ROWS_PER_TILE;

        // ---- stage 256 rows x 20 floats, fully coalesced float4 loads ----
        const float4* src = reinterpret_cast<const float4*>(pCS + (size_t)base * 20);
        #pragma unroll
        for (int k = 0; k < 5; ++k) {
            int g = tid + (k << 8);            // float4 index in tile, 0..1279
            int r = g / 5;                     // row within tile (each row = 5 float4)
            int j = g - r * 5;                 // which float4 of the row
            float4 v = make_float4(0.f, 0.f, 0.f, 0.f);
            if (base + r < B) v = src[g];
            float* dst = &sp[r * ROW_PAD + j * 4];
            dst[0] = v.x; dst[1] = v.y; dst[2] = v.z; dst[3] = v.w;
        }
        __syncthreads();

        const int row = base + tid;
        if (row < B) {
            const float* my = &sp[tid * ROW_PAD];
            float p1[K_CONST], p2[K_CONST], lg1[K_CONST], lg2[K_CONST];
            #pragma unroll
            for (int j = 0; j < K_CONST; ++j) { p1[j] = my[j]; p2[j] = my[10 + j]; }
            #pragma unroll
            for (int j = 0; j < K_CONST; ++j) {
                lg1[j] = logf(p1[j]);          // p >= ~1e-4 >> 1e-8, log(p+eps)~log(p)
                lg2[j] = logf(p2[j]);
                ent += p1[j] * lg1[j] + p2[j] * lg2[j];
            }

            const int y = Y[row];

            int a1[S_CONST], a2[S_CONST], pr[S_CONST];
            float c[S_CONST];
            float csum = 0.f;
            #pragma unroll
            for (int s = 0; s < S_CONST; ++s) {
                a1[s] = s1g[(size_t)s * B + row];
                a2[s] = s2g[(size_t)s * B + row];
                pr[s] = a1[s] * K_CONST + a2[s];
                c[s]  = (a1[s] + a2[s] == y) ? 1.f : 0.f;
                csum += c[s];
            }
            corr += csum;

            #pragma unroll
            for (int i = 0; i < S_CONST; ++i) {
                bool dup = false;
                #pragma unroll
                for (int j = 0; j < i; ++j) dup = dup || (pr[i] == pr[j]);
                uniq += dup ? 0.f : 1.f;
            }

            #pragma unroll
            for (int s = 0; s < S_CONST; ++s) {
                float adv = c[s] - (csum - c[s]) / 7.0f;
                float g1 = lg1[0], g2 = lg2[0];
                #pragma unroll
                for (int j = 1; j < K_CONST; ++j) {
                    g1 = (a1[s] == j) ? lg1[j] : g1;
                    g2 = (a2[s] == j) ? lg2[j] : g2;
                }
                rloo += (g1 + g2) * adv;
            }
        }
        __syncthreads();   // protect sp before next tile overwrites it
    }

    // ---- 64-lane butterfly ----
    #pragma unroll
    for (int off = 32; off >= 1; off >>= 1) {
        ent  += __shfl_xor(ent,  off);
        uniq += __shfl_xor(uniq, off);
        corr += __shfl_xor(corr, off);
        rloo += __shfl_xor(rloo, off);
    }

    const int lane = threadIdx.x & 63;
    const int wave = threadIdx.x >> 6;
    if (lane == 0) {
        red[wave][0] = ent; red[wave][1] = uniq;
        red[wave][2] = corr; red[wave][3] = rloo;
    }
    __syncthreads();
    if (threadIdx.x == 0) {
        double e = 0, u = 0, cs = 0, rl = 0;
        #pragma unroll
        for (int w = 0; w < 4; ++w) {
            e += (double)red[w][0]; u += (double)red[w][1];
            cs += (double)red[w][2]; rl += (double)red[w][3];
        }
        double* p = &partials[(size_t)blockIdx.x * 4];
        p[0] = e; p[1] = u; p[2] = cs; p[3] = rl;
    }
}

__global__ __launch_bounds__(1024) void fml_finalize(
        const double* __restrict__ partials,
        const float* __restrict__ base_loss,
        float* __restrict__ out, int B, int nblocks)
{
    __shared__ double red[16][4];
    double e = 0, u = 0, cs = 0, rl = 0;
    for (int i = threadIdx.x; i < nblocks; i += 1024) {
        const double* p = &partials[(size_t)i * 4];
        e += p[0]; u += p[1]; cs += p[2]; rl += p[3];
    }
    #pragma unroll
    for (int off = 32; off >= 1; off >>= 1) {
        e  += __shfl_xor(e,  off);
        u  += __shfl_xor(u,  off);
        cs += __shfl_xor(cs, off);
        rl += __shfl_xor(rl, off);
    }
    const int lane = threadIdx.x & 63;
    const int wave = threadIdx.x >> 6;
    if (lane == 0) { red[wave][0] = e; red[wave][1] = u; red[wave][2] = cs; red[wave][3] = rl; }
    __syncthreads();
    if (threadIdx.x == 0) {
        e = 0; u = 0; cs = 0; rl = 0;
        #pragma unroll
        for (int w = 0; w < 16; ++w) {
            e += red[w][0]; u += red[w][1]; cs += red[w][2]; rl += red[w][3];
        }
        double dB = (double)B;
        // ent accumulated sum_b sum_j (p1 logp1 + p2 logp2); entropy_loss = ent/(2B)
        float entropy_loss = (float)(e / (2.0 * dB));
        float diversity = (float)(u / dB);
        float ratio = diversity / 8.0f;                  // max_diversity = min(8,100)=8
        float diversity_loss = -logf(ratio + EPSF);
        float sample_acc = (float)(cs / (dB * (double)S_CONST));
        float rloo_loss  = (float)(-rl / (dB * (double)S_CONST));
        out[0] = base_loss[0] + 0.01f * entropy_loss + 0.1f * diversity_loss;
        out[1] = rloo_loss;
        out[2] = diversity_loss;
        out[3] = sample_acc;
    }
}

extern "C" void kernel_launch(void* const* d_in, const int* in_sizes, int n_in,
                              void* d_out, int out_size, void* d_ws, size_t ws_size,
                              hipStream_t stream) {
    const float* pCS       = (const float*)d_in[0];
    const float* base_loss = (const float*)d_in[1];
    const int*   Y         = (const int*)d_in[2];
    const int*   s1        = (const int*)d_in[3];
    const int*   s2        = (const int*)d_in[4];
    float* out = (float*)d_out;
    const int B = in_sizes[2];

    double* partials = (double*)d_ws;   // 2048 * 4 doubles = 64 KB

    const int block = 256;
    const int grid = 2048;              // 2 tiles of 256 rows per block at B=1M
    fml_reduce<<<grid, block, 0, stream>>>(pCS, Y, s1, s2, partials, B);
    fml_finalize<<<1, 1024, 0, stream>>>(partials, base_loss, out, B, grid);
}

// Round 3
// 42.715 us; speedup vs baseline: 3.4196x; 1.0417x over previous
//
#include <hip/hip_runtime.h>

#define S_CONST 8
#define K_CONST 10
#define EPSF 1e-8f
#define ROWS 256   // rows per tile; 20 floats/row -> 20480 B LDS, 7 blocks/CU

// partials[nblocks][4] doubles: {sum p*logp (both heads), uniq, corr, rloo}
__global__ __launch_bounds__(256) void fml_reduce(
        const float* __restrict__ pCS,
        const int* __restrict__ Y,
        const int* __restrict__ s1g,
        const int* __restrict__ s2g,
        double* __restrict__ partials,
        int B)
{
    __shared__ float sp[ROWS * 20];    // flat copy of the 256-row chunk (pad-free)
    __shared__ float red[4][4];

    float ent = 0.f, uniq = 0.f, corr = 0.f, rloo = 0.f;
    const int tid = threadIdx.x;
    const int ntiles = (B + ROWS - 1) / ROWS;

    for (int tile = blockIdx.x; tile < ntiles; tile += gridDim.x) {
        const int base = tile * ROWS;

        // ---- stage 256 rows x 20 floats, coalesced float4, fuse entropy ----
        const float4* src = reinterpret_cast<const float4*>(pCS + (size_t)base * 20);
        float4* dst = reinterpret_cast<float4*>(sp);
        const bool full = (base + ROWS) <= B;
        #pragma unroll
        for (int k = 0; k < 5; ++k) {
            const int g = tid + (k << 8);              // float4 index, 0..1279
            float4 v = make_float4(1.f, 1.f, 1.f, 1.f); // log(1)=0 padding
            if (full || (base + g / 5) < B) v = src[g];
            // entropy: order-independent global sum of p*log(p)
            ent += v.x * __logf(v.x) + v.y * __logf(v.y)
                 + v.z * __logf(v.z) + v.w * __logf(v.w);
            dst[g] = v;                                 // ds_write_b128, conflict-free
        }
        __syncthreads();

        const int row = base + tid;
        if (row < B) {
            const int y = Y[row];

            int a1[S_CONST], a2[S_CONST], pr[S_CONST];
            float c[S_CONST];
            float csum = 0.f;
            #pragma unroll
            for (int s = 0; s < S_CONST; ++s) {
                a1[s] = s1g[(size_t)s * B + row];
                a2[s] = s2g[(size_t)s * B + row];
                pr[s] = a1[s] * K_CONST + a2[s];
                c[s]  = (a1[s] + a2[s] == y) ? 1.f : 0.f;
                csum += c[s];
            }
            corr += csum;

            #pragma unroll
            for (int i = 0; i < S_CONST; ++i) {
                bool dup = false;
                #pragma unroll
                for (int j = 0; j < i; ++j) dup = dup || (pr[i] == pr[j]);
                uniq += dup ? 0.f : 1.f;
            }

            // rloo: gather staged p from LDS, one log per sample
            const float* my = &sp[tid * 20];
            #pragma unroll
            for (int s = 0; s < S_CONST; ++s) {
                const float g1 = my[a1[s]];            // ds_read_b32 gather
                const float g2 = my[10 + a2[s]];
                const float adv = c[s] - (csum - c[s]) / 7.0f;
                rloo += __logf(g1 * g2) * adv;         // log p1 + log p2 = log(p1*p2)
            }
        }
        __syncthreads();   // protect sp before next tile overwrites it
    }

    // ---- 64-lane butterfly ----
    #pragma unroll
    for (int off = 32; off >= 1; off >>= 1) {
        ent  += __shfl_xor(ent,  off);
        uniq += __shfl_xor(uniq, off);
        corr += __shfl_xor(corr, off);
        rloo += __shfl_xor(rloo, off);
    }

    const int lane = threadIdx.x & 63;
    const int wave = threadIdx.x >> 6;
    if (lane == 0) {
        red[wave][0] = ent; red[wave][1] = uniq;
        red[wave][2] = corr; red[wave][3] = rloo;
    }
    __syncthreads();
    if (threadIdx.x == 0) {
        double e = 0, u = 0, cs = 0, rl = 0;
        #pragma unroll
        for (int w = 0; w < 4; ++w) {
            e += (double)red[w][0]; u += (double)red[w][1];
            cs += (double)red[w][2]; rl += (double)red[w][3];
        }
        double* p = &partials[(size_t)blockIdx.x * 4];
        p[0] = e; p[1] = u; p[2] = cs; p[3] = rl;
    }
}

__global__ __launch_bounds__(1024) void fml_finalize(
        const double* __restrict__ partials,
        const float* __restrict__ base_loss,
        float* __restrict__ out, int B, int nblocks)
{
    __shared__ double red[16][4];
    double e = 0, u = 0, cs = 0, rl = 0;
    for (int i = threadIdx.x; i < nblocks; i += 1024) {
        const double* p = &partials[(size_t)i * 4];
        e += p[0]; u += p[1]; cs += p[2]; rl += p[3];
    }
    #pragma unroll
    for (int off = 32; off >= 1; off >>= 1) {
        e  += __shfl_xor(e,  off);
        u  += __shfl_xor(u,  off);
        cs += __shfl_xor(cs, off);
        rl += __shfl_xor(rl, off);
    }
    const int lane = threadIdx.x & 63;
    const int wave = threadIdx.x >> 6;
    if (lane == 0) { red[wave][0] = e; red[wave][1] = u; red[wave][2] = cs; red[wave][3] = rl; }
    __syncthreads();
    if (threadIdx.x == 0) {
        e = 0; u = 0; cs = 0; rl = 0;
        #pragma unroll
        for (int w = 0; w < 16; ++w) {
            e += red[w][0]; u += red[w][1]; cs += red[w][2]; rl += red[w][3];
        }
        const double dB = (double)B;
        const float entropy_loss = (float)(e / (2.0 * dB));   // = -(ent1+ent2)/2
        const float diversity = (float)(u / dB);
        const float ratio = diversity / 8.0f;                 // max_diversity = 8
        const float diversity_loss = -logf(ratio + EPSF);
        const float sample_acc = (float)(cs / (dB * (double)S_CONST));
        const float rloo_loss  = (float)(-rl / (dB * (double)S_CONST));
        out[0] = base_loss[0] + 0.01f * entropy_loss + 0.1f * diversity_loss;
        out[1] = rloo_loss;
        out[2] = diversity_loss;
        out[3] = sample_acc;
    }
}

extern "C" void kernel_launch(void* const* d_in, const int* in_sizes, int n_in,
                              void* d_out, int out_size, void* d_ws, size_t ws_size,
                              hipStream_t stream) {
    const float* pCS       = (const float*)d_in[0];
    const float* base_loss = (const float*)d_in[1];
    const int*   Y         = (const int*)d_in[2];
    const int*   s1        = (const int*)d_in[3];
    const int*   s2        = (const int*)d_in[4];
    float* out = (float*)d_out;
    const int B = in_sizes[2];

    double* partials = (double*)d_ws;   // 2048 * 4 doubles = 64 KB (fits round-2 ws)

    const int block = 256;
    const int grid = 2048;              // 2 tiles of 256 rows per block at B=1M
    fml_reduce<<<grid, block, 0, stream>>>(pCS, Y, s1, s2, partials, B);
    fml_finalize<<<1, 1024, 0, stream>>>(partials, base_loss, out, B, grid);
}

// Round 4
// 38.150 us; speedup vs baseline: 3.8289x; 1.1197x over previous
//
#include <hip/hip_runtime.h>

#define S_CONST 8
#define K_CONST 10
#define EPSF 1e-8f

// partials[nblocks][4] doubles: {sum p*logp (both heads), uniq, corr, rloo}
__global__ __launch_bounds__(256) void fml_reduce(
        const float* __restrict__ pCS,
        const int* __restrict__ Y,
        const int* __restrict__ s1g,
        const int* __restrict__ s2g,
        double* __restrict__ partials,
        int B)
{
    __shared__ float sp[4][64 * 20];   // one private 64-row panel per wave, 20.0 KiB
    __shared__ float red[4][4];

    const int lane = threadIdx.x & 63;
    const int wv   = threadIdx.x >> 6;
    float* sw = sp[wv];

    float ent = 0.f, uniq = 0.f, corr = 0.f, rloo = 0.f;

    const int nchunks = (B + 63) >> 6;          // 64-row chunks, one per wave-iter
    const int gwaves  = gridDim.x << 2;
    for (int ch = (blockIdx.x << 2) + wv; ch < nchunks; ch += gwaves) {
        const int base = ch << 6;
        const int row  = base + lane;
        const bool full = (base + 64) <= B;     // always true when 64 | B
        const bool inb  = full || (row < B);

        // ---- issue scattered loads FIRST: latency hides under staging ----
        int y = 0;
        int a1[S_CONST], a2[S_CONST];
        if (inb) {
            y = Y[row];
            #pragma unroll
            for (int s = 0; s < S_CONST; ++s) {
                a1[s] = s1g[(size_t)s * B + row];
                a2[s] = s2g[(size_t)s * B + row];
            }
        } else {
            y = -1;
            #pragma unroll
            for (int s = 0; s < S_CONST; ++s) { a1[s] = 0; a2[s] = 0; }
        }

        // ---- stage this wave's 64 rows (320 float4), entropy fused ----
        const float4* src = reinterpret_cast<const float4*>(pCS + (size_t)base * 20);
        float4* dst = reinterpret_cast<float4*>(sw);
        #pragma unroll
        for (int k = 0; k < 5; ++k) {
            const int g = lane + (k << 6);
            float4 v = make_float4(1.f, 1.f, 1.f, 1.f);   // log(1)=0 padding (tail only)
            if (full || (base + g / 5) < B) v = src[g];
            ent += v.x * __logf(v.x) + v.y * __logf(v.y)
                 + v.z * __logf(v.z) + v.w * __logf(v.w);
            dst[g] = v;                                   // ds_write_b128
        }
        // wave-synchronous LDS: same-wave write->read is ordered by lgkmcnt;
        // scheduling fence only, no s_barrier, zero cost.
        __builtin_amdgcn_wave_barrier();

        if (inb) {
            int pr[S_CONST];
            float c[S_CONST];
            float csum = 0.f;
            #pragma unroll
            for (int s = 0; s < S_CONST; ++s) {
                pr[s] = a1[s] * K_CONST + a2[s];
                c[s]  = (a1[s] + a2[s] == y) ? 1.f : 0.f;
                csum += c[s];
            }
            corr += csum;

            #pragma unroll
            for (int i = 0; i < S_CONST; ++i) {
                bool dup = false;
                #pragma unroll
                for (int j = 0; j < i; ++j) dup = dup || (pr[i] == pr[j]);
                uniq += dup ? 0.f : 1.f;
            }

            // rloo: gather own row from the wave's panel, one log per sample
            const float* my = &sw[lane * 20];
            #pragma unroll
            for (int s = 0; s < S_CONST; ++s) {
                const float g1 = my[a1[s]];               // ds_read_b32 gather
                const float g2 = my[10 + a2[s]];
                const float adv = c[s] - (csum - c[s]) / 7.0f;
                rloo += __logf(g1 * g2) * adv;            // log p1 + log p2
            }
        }
        __builtin_amdgcn_wave_barrier();   // keep next iter's writes behind reads
    }

    // ---- 64-lane butterfly ----
    #pragma unroll
    for (int off = 32; off >= 1; off >>= 1) {
        ent  += __shfl_xor(ent,  off);
        uniq += __shfl_xor(uniq, off);
        corr += __shfl_xor(corr, off);
        rloo += __shfl_xor(rloo, off);
    }

    if (lane == 0) {
        red[wv][0] = ent; red[wv][1] = uniq;
        red[wv][2] = corr; red[wv][3] = rloo;
    }
    __syncthreads();                       // once per kernel, not per tile
    if (threadIdx.x == 0) {
        double e = 0, u = 0, cs = 0, rl = 0;
        #pragma unroll
        for (int w = 0; w < 4; ++w) {
            e += (double)red[w][0]; u += (double)red[w][1];
            cs += (double)red[w][2]; rl += (double)red[w][3];
        }
        double* p = &partials[(size_t)blockIdx.x * 4];
        p[0] = e; p[1] = u; p[2] = cs; p[3] = rl;
    }
}

__global__ __launch_bounds__(1024) void fml_finalize(
        const double* __restrict__ partials,
        const float* __restrict__ base_loss,
        float* __restrict__ out, int B, int nblocks)
{
    __shared__ double red[16][4];
    double e = 0, u = 0, cs = 0, rl = 0;
    for (int i = threadIdx.x; i < nblocks; i += 1024) {
        const double* p = &partials[(size_t)i * 4];
        e += p[0]; u += p[1]; cs += p[2]; rl += p[3];
    }
    #pragma unroll
    for (int off = 32; off >= 1; off >>= 1) {
        e  += __shfl_xor(e,  off);
        u  += __shfl_xor(u,  off);
        cs += __shfl_xor(cs, off);
        rl += __shfl_xor(rl, off);
    }
    const int lane = threadIdx.x & 63;
    const int wave = threadIdx.x >> 6;
    if (lane == 0) { red[wave][0] = e; red[wave][1] = u; red[wave][2] = cs; red[wave][3] = rl; }
    __syncthreads();
    if (threadIdx.x == 0) {
        e = 0; u = 0; cs = 0; rl = 0;
        #pragma unroll
        for (int w = 0; w < 16; ++w) {
            e += red[w][0]; u += red[w][1]; cs += red[w][2]; rl += red[w][3];
        }
        const double dB = (double)B;
        const float entropy_loss = (float)(e / (2.0 * dB));   // = -(ent1+ent2)/2
        const float diversity = (float)(u / dB);
        const float ratio = diversity / 8.0f;                 // max_diversity = 8
        const float diversity_loss = -logf(ratio + EPSF);
        const float sample_acc = (float)(cs / (dB * (double)S_CONST));
        const float rloo_loss  = (float)(-rl / (dB * (double)S_CONST));
        out[0] = base_loss[0] + 0.01f * entropy_loss + 0.1f * diversity_loss;
        out[1] = rloo_loss;
        out[2] = diversity_loss;
        out[3] = sample_acc;
    }
}

extern "C" void kernel_launch(void* const* d_in, const int* in_sizes, int n_in,
                              void* d_out, int out_size, void* d_ws, size_t ws_size,
                              hipStream_t stream) {
    const float* pCS       = (const float*)d_in[0];
    const float* base_loss = (const float*)d_in[1];
    const int*   Y         = (const int*)d_in[2];
    const int*   s1        = (const int*)d_in[3];
    const int*   s2        = (const int*)d_in[4];
    float* out = (float*)d_out;
    const int B = in_sizes[2];

    double* partials = (double*)d_ws;   // 2048 * 4 doubles = 64 KB (proven safe)

    const int block = 256;
    const int grid = 2048;              // 8192 waves, 2 chunks of 64 rows each
    fml_reduce<<<grid, block, 0, stream>>>(pCS, Y, s1, s2, partials, B);
    fml_finalize<<<1, 1024, 0, stream>>>(partials, base_loss, out, B, grid);
}

// Round 5
// 36.376 us; speedup vs baseline: 4.0156x; 1.0488x over previous
//
#include <hip/hip_runtime.h>

#define S_CONST 8
#define K_CONST 10
#define EPSF 1e-8f

struct Samp { int y; int a1[S_CONST]; int a2[S_CONST]; };

__device__ __forceinline__ void load_samp(Samp& sm, const int* __restrict__ Y,
                                          const int* __restrict__ s1g,
                                          const int* __restrict__ s2g,
                                          int B, int row, bool inb) {
    if (inb) {
        sm.y = Y[row];
        #pragma unroll
        for (int s = 0; s < S_CONST; ++s) {
            sm.a1[s] = s1g[(size_t)s * B + row];
            sm.a2[s] = s2g[(size_t)s * B + row];
        }
    } else {
        sm.y = -1;
        #pragma unroll
        for (int s = 0; s < S_CONST; ++s) { sm.a1[s] = 0; sm.a2[s] = 0; }
    }
}

__device__ __forceinline__ void load_pcs(const float* __restrict__ pCS, int base, int B,
                                         bool full, float4 v[5], int lane) {
    const float4* src = reinterpret_cast<const float4*>(pCS + (size_t)base * 20);
    #pragma unroll
    for (int k = 0; k < 5; ++k) {
        const int g = lane + (k << 6);
        float4 t = make_float4(1.f, 1.f, 1.f, 1.f);    // log(1)=0 padding (tail only)
        if (full || (base + g / 5) < B) t = src[g];
        v[k] = t;
    }
}

// entropy from registers + write LOG panel (rloo gathers logs directly)
__device__ __forceinline__ float ent_write(float* __restrict__ pan,
                                           const float4 v[5], int lane) {
    float e = 0.f;
    float4* dst = reinterpret_cast<float4*>(pan);
    #pragma unroll
    for (int k = 0; k < 5; ++k) {
        float4 lg;
        lg.x = __logf(v[k].x); lg.y = __logf(v[k].y);
        lg.z = __logf(v[k].z); lg.w = __logf(v[k].w);
        e += v[k].x * lg.x + v[k].y * lg.y + v[k].z * lg.z + v[k].w * lg.w;
        dst[lane + (k << 6)] = lg;                      // ds_write_b128
    }
    return e;
}

__device__ __forceinline__ void body(const float* __restrict__ pan, const Samp& sm,
                                     bool inb, int lane,
                                     float& uniq, float& corr, float& rloo) {
    if (!inb) return;
    int pr[S_CONST]; float c[S_CONST];
    float csum = 0.f;
    #pragma unroll
    for (int s = 0; s < S_CONST; ++s) {
        pr[s] = sm.a1[s] * K_CONST + sm.a2[s];
        c[s]  = (sm.a1[s] + sm.a2[s] == sm.y) ? 1.f : 0.f;
        csum += c[s];
    }
    corr += csum;

    #pragma unroll
    for (int i = 0; i < S_CONST; ++i) {
        bool dup = false;
        #pragma unroll
        for (int j = 0; j < i; ++j) dup = dup || (pr[i] == pr[j]);
        uniq += dup ? 0.f : 1.f;
    }

    const float* my = &pan[lane * 20];
    const float cs7 = csum * (1.0f / 7.0f);
    #pragma unroll
    for (int s = 0; s < S_CONST; ++s) {
        const float lp = my[sm.a1[s]] + my[10 + sm.a2[s]];   // gathered logs
        const float adv = c[s] * (8.0f / 7.0f) - cs7;        // c - (csum-c)/7
        rloo += lp * adv;
    }
}

// partials[nblocks][4]: {sum p*logp (both heads), uniq, corr, rloo}
__global__ __launch_bounds__(256) void fml_reduce(
        const float* __restrict__ pCS,
        const int* __restrict__ Y,
        const int* __restrict__ s1g,
        const int* __restrict__ s2g,
        double* __restrict__ partials,
        int B)
{
    __shared__ float lgpan[4][64 * 20];   // per-wave log panel, 5 KiB each
    __shared__ float red[4][4];

    const int lane = threadIdx.x & 63;
    const int wv   = threadIdx.x >> 6;
    float* pan = lgpan[wv];

    const int nchunks = (B + 63) >> 6;
    const int wid = (blockIdx.x << 2) + wv;
    const int ch0 = wid * 2, ch1 = wid * 2 + 1;
    const bool has0 = ch0 < nchunks, has1 = ch1 < nchunks;
    const int base0 = ch0 << 6, base1 = ch1 << 6;
    const bool full0 = has0 && (base0 + 64 <= B);
    const bool full1 = has1 && (base1 + 64 <= B);
    const bool inb0  = has0 && (full0 || base0 + lane < B);
    const bool inb1  = has1 && (full1 || base1 + lane < B);

    float ent = 0.f, uniq = 0.f, corr = 0.f, rloo = 0.f;
    float4 v0[5], v1[5];
    Samp sm0, sm1;

    // ---- issue-early: ch0 pCS, ch0 samples, ch1 pCS all in flight ----
    if (has0) load_pcs(pCS, base0, B, full0, v0, lane);
    load_samp(sm0, Y, s1g, s2g, B, base0 + lane, inb0);
    if (has1) load_pcs(pCS, base1, B, full1, v1, lane);

    // ---- chunk 0: entropy + log-panel write (waits only on v0) ----
    if (has0) ent += ent_write(pan, v0, lane);
    // issue ch1 samples now: ~600cy of ch0 compute left to hide them
    load_samp(sm1, Y, s1g, s2g, B, base1 + lane, inb1);
    __builtin_amdgcn_wave_barrier();
    body(pan, sm0, inb0, lane, uniq, corr, rloo);
    __builtin_amdgcn_wave_barrier();     // ch1 panel writes stay behind ch0 gathers

    // ---- chunk 1 (pCS already resident in registers) ----
    if (has1) ent += ent_write(pan, v1, lane);
    __builtin_amdgcn_wave_barrier();
    body(pan, sm1, inb1, lane, uniq, corr, rloo);

    // ---- 64-lane butterfly ----
    #pragma unroll
    for (int off = 32; off >= 1; off >>= 1) {
        ent  += __shfl_xor(ent,  off);
        uniq += __shfl_xor(uniq, off);
        corr += __shfl_xor(corr, off);
        rloo += __shfl_xor(rloo, off);
    }

    if (lane == 0) {
        red[wv][0] = ent; red[wv][1] = uniq;
        red[wv][2] = corr; red[wv][3] = rloo;
    }
    __syncthreads();
    if (threadIdx.x == 0) {
        double e = 0, u = 0, cs = 0, rl = 0;
        #pragma unroll
        for (int w = 0; w < 4; ++w) {
            e += (double)red[w][0]; u += (double)red[w][1];
            cs += (double)red[w][2]; rl += (double)red[w][3];
        }
        double* p = &partials[(size_t)blockIdx.x * 4];
        p[0] = e; p[1] = u; p[2] = cs; p[3] = rl;
    }
}

__global__ __launch_bounds__(1024) void fml_finalize(
        const double* __restrict__ partials,
        const float* __restrict__ base_loss,
        float* __restrict__ out, int B, int nblocks)
{
    __shared__ double red[16][4];
    double e = 0, u = 0, cs = 0, rl = 0;
    for (int i = threadIdx.x; i < nblocks; i += 1024) {
        const double* p = &partials[(size_t)i * 4];
        e += p[0]; u += p[1]; cs += p[2]; rl += p[3];
    }
    #pragma unroll
    for (int off = 32; off >= 1; off >>= 1) {
        e  += __shfl_xor(e,  off);
        u  += __shfl_xor(u,  off);
        cs += __shfl_xor(cs, off);
        rl += __shfl_xor(rl, off);
    }
    const int lane = threadIdx.x & 63;
    const int wave = threadIdx.x >> 6;
    if (lane == 0) { red[wave][0] = e; red[wave][1] = u; red[wave][2] = cs; red[wave][3] = rl; }
    __syncthreads();
    if (threadIdx.x == 0) {
        e = 0; u = 0; cs = 0; rl = 0;
        #pragma unroll
        for (int w = 0; w < 16; ++w) {
            e += red[w][0]; u += red[w][1]; cs += red[w][2]; rl += red[w][3];
        }
        const double dB = (double)B;
        const float entropy_loss = (float)(e / (2.0 * dB));   // = -(ent1+ent2)/2
        const float diversity = (float)(u / dB);
        const float ratio = diversity / 8.0f;                 // max_diversity = 8
        const float diversity_loss = -logf(ratio + EPSF);
        const float sample_acc = (float)(cs / (dB * (double)S_CONST));
        const float rloo_loss  = (float)(-rl / (dB * (double)S_CONST));
        out[0] = base_loss[0] + 0.01f * entropy_loss + 0.1f * diversity_loss;
        out[1] = rloo_loss;
        out[2] = diversity_loss;
        out[3] = sample_acc;
    }
}

extern "C" void kernel_launch(void* const* d_in, const int* in_sizes, int n_in,
                              void* d_out, int out_size, void* d_ws, size_t ws_size,
                              hipStream_t stream) {
    const float* pCS       = (const float*)d_in[0];
    const float* base_loss = (const float*)d_in[1];
    const int*   Y         = (const int*)d_in[2];
    const int*   s1        = (const int*)d_in[3];
    const int*   s2        = (const int*)d_in[4];
    float* out = (float*)d_out;
    const int B = in_sizes[2];

    double* partials = (double*)d_ws;

    const int nchunks = (B + 63) >> 6;
    const int waves   = (nchunks + 1) >> 1;        // 2 chunks per wave
    const int blocks  = (waves + 3) >> 2;          // 4 waves per block (2048 @ B=1M)

    fml_reduce<<<blocks, 256, 0, stream>>>(pCS, Y, s1, s2, partials, B);
    fml_finalize<<<1, 1024, 0, stream>>>(partials, base_loss, out, B, blocks);
}